// Round 1
// 921.608 us; speedup vs baseline: 1.2245x; 1.2245x over previous
//
#include <hip/hip_runtime.h>
#include <stdint.h>

typedef unsigned short u16;
typedef short s16x8 __attribute__((ext_vector_type(8)));
typedef float f32x4 __attribute__((ext_vector_type(4)));

__device__ __forceinline__ u16 f2bf(float f) {
    union { float f; uint32_t i; } v; v.f = f;
    return (u16)((v.i + 0x7FFFu + ((v.i >> 16) & 1u)) >> 16);
}

__global__ void __launch_bounds__(256) cvt_f32_bf16(
    const float* __restrict__ src, u16* __restrict__ dst, int n4)
{
    int i = blockIdx.x * 256 + threadIdx.x;
    if (i >= n4) return;
    float4 f = ((const float4*)src)[i];
    ushort4 o;
    o.x = f2bf(f.x); o.y = f2bf(f.y); o.z = f2bf(f.z); o.w = f2bf(f.w);
    ((ushort4*)dst)[i] = o;
}

#define ASYNC_LD16(gp, lp)                                                       \
    __builtin_amdgcn_global_load_lds(                                            \
        (const __attribute__((address_space(1))) uint32_t*)(gp),                 \
        (__attribute__((address_space(3))) uint32_t*)(lp), 16, 0, 0)

// ---------------------------------------------------------------------------
// Small-GEMM kernel (kept from previous round, verified): 128x128 tile.
// MODE 0: c += bias[col]; e=exp(c); store bf16; atomicAdd row-sums of e.
// MODE 1: c += bias[row]; store bf16 relu(c).
template <int MODE>
__global__ void __launch_bounds__(256) gemm_bt(
    const u16* __restrict__ A, const u16* __restrict__ B, int K, int N,
    u16* __restrict__ C, float* __restrict__ Cf,
    const float* __restrict__ bias,
    const float* __restrict__ sv, float* __restrict__ sum_out)
{
    __shared__ __align__(16) u16 As[128 * 32];
    __shared__ __align__(16) u16 Bs[128 * 32];

    const int tid  = threadIdx.x;
    const int lane = tid & 63;
    const int wave = tid >> 6;
    const int wx = wave & 1, wy = wave >> 1;
    const int lr = lane & 15, lq = lane >> 4;
    const int m0 = blockIdx.y * 128, n0 = blockIdx.x * 128;

    f32x4 acc[4][4] = {};

    const int srow = tid >> 2;
    const int scol = (tid & 3) * 8;
    const u16* gA = A + (size_t)(m0 + srow) * K + scol;
    const u16* gB = B + (size_t)(n0 + srow) * K + scol;
    const size_t rstep = (size_t)64 * K;
    u16* lA0 = &As[wave * 512];
    u16* lA1 = &As[2048 + wave * 512];
    u16* lB0 = &Bs[wave * 512];
    u16* lB1 = &Bs[2048 + wave * 512];

    const u16* pa = &As[(wy * 64 + lr) * 32 + lq * 8];
    const u16* pb = &Bs[(wx * 64 + lr) * 32 + lq * 8];

    for (int k0 = 0; k0 < K; k0 += 32) {
        ASYNC_LD16(gA + k0, lA0);
        ASYNC_LD16(gA + k0 + rstep, lA1);
        ASYNC_LD16(gB + k0, lB0);
        ASYNC_LD16(gB + k0 + rstep, lB1);
        __syncthreads();
        s16x8 af[4], bfr[4];
#pragma unroll
        for (int i = 0; i < 4; ++i) {
            af[i]  = *(const s16x8*)(pa + i * 512);
            bfr[i] = *(const s16x8*)(pb + i * 512);
        }
#pragma unroll
        for (int mi = 0; mi < 4; ++mi)
#pragma unroll
            for (int ni = 0; ni < 4; ++ni)
                acc[mi][ni] = __builtin_amdgcn_mfma_f32_16x16x32_bf16(
                    af[mi], bfr[ni], acc[mi][ni], 0, 0, 0);
        __syncthreads();
    }

    const int rowB = m0 + wy * 64 + lq * 4;
    const int colB = n0 + wx * 64 + lr;

    if constexpr (MODE == 0) {
        float bcol[4];
#pragma unroll
        for (int ni = 0; ni < 4; ++ni) bcol[ni] = bias[colB + ni * 16];
#pragma unroll
        for (int mi = 0; mi < 4; ++mi)
#pragma unroll
            for (int r = 0; r < 4; ++r) {
                const int gm = rowB + mi * 16 + r;
                float s = 0.f;
#pragma unroll
                for (int ni = 0; ni < 4; ++ni) {
                    float e = __expf(acc[mi][ni][r] + bcol[ni]);
                    C[(size_t)gm * N + (colB + ni * 16)] = f2bf(e);
                    s += e;
                }
                s += __shfl_xor(s, 1);
                s += __shfl_xor(s, 2);
                s += __shfl_xor(s, 4);
                s += __shfl_xor(s, 8);
                if (lr == 0) atomicAdd(&sum_out[gm], s);
            }
    } else {
#pragma unroll
        for (int mi = 0; mi < 4; ++mi)
#pragma unroll
            for (int r = 0; r < 4; ++r) {
                const int gm = rowB + mi * 16 + r;
                const float b = bias[gm];
#pragma unroll
                for (int ni = 0; ni < 4; ++ni) {
                    float c = acc[mi][ni][r] + b;
                    C[(size_t)gm * N + (colB + ni * 16)] = f2bf(c > 0.f ? c : 0.f);
                }
            }
    }
}

// ---------------------------------------------------------------------------
// Big-GEMM kernel: 256x256 tile, 8 waves, BK=32, 4-deep LDS ring (128 KiB),
// 2 phases/K-tile, counted vmcnt(8) (never 0 in loop), setprio around MFMA,
// both-sides XOR swizzle for conflict-free ds_read_b128, XCD block swizzle.
// MODE 2: e = exp(c / sv[col]); store bf16; atomicAdd row-sums of e.
// MODE 3: store fp32 (c / sv[row]) to Cf.
//
// Race-freedom argument:
//   WAR: prefetch for K-tile c+3 (buffer (c+3)&3 == (c-1)&3) is issued in
//        iteration c, i.e. after the trailing barrier of iteration c-1; every
//        wave's ds_reads of that buffer completed (lgkmcnt(0)) before it
//        reached that barrier, so the buffer is free when the write can land.
//   RAW: the single vmcnt(8) at the end of iteration c leaves at most the
//        8 loads of K-tiles c+2,c+3 outstanding => K-tile c+1 has fully
//        landed before the trailing barrier; next iteration's ds_reads
//        happen after that barrier.
template <int MODE>
__global__ void __launch_bounds__(512, 2) gemm256_bt(
    const u16* __restrict__ A, const u16* __restrict__ B, int K, int N,
    u16* __restrict__ C, float* __restrict__ Cf,
    const float* __restrict__ sv, float* __restrict__ sum_out, int nbx)
{
    __shared__ __align__(16) u16 lds[4 * 16384];   // 4 bufs x (A 16K + B 16K) B

    const int tid  = threadIdx.x;
    const int lane = tid & 63;
    const int wave = tid >> 6;          // 0..7
    const int wr = wave >> 2;           // 0..1 : 128-row half
    const int wc = wave & 3;            // 0..3 : 64-col quarter
    const int fr = lane & 15;
    const int lq = lane >> 4;

    // XCD-aware bijective swizzle (gridDim.x % 8 == 0 for both uses)
    const int nwg = gridDim.x;
    const int swz = ((int)blockIdx.x & 7) * (nwg >> 3) + ((int)blockIdx.x >> 3);
    const int bx = swz % nbx, by = swz / nbx;
    const int m0 = by * 256, n0 = bx * 256;

    // ---- staging addressing: linear LDS dest, pre-swizzled global source.
    // LDS chunk l (16B units) = round*512 + tid; row = l>>2, c2 = l&3.
    // LDS (row,c2) holds global chunk  c2 ^ ((row>>1)&3).
    const int r0 = tid >> 2;            // rows 0..127 (round 0)
    const int r1 = r0 + 128;            // rows 128..255 (round 1), same xor
    const int gch = (tid & 3) ^ ((r0 >> 1) & 3);
    const u16* gA0 = A + (size_t)(m0 + r0) * K + gch * 8;
    const u16* gA1 = A + (size_t)(m0 + r1) * K + gch * 8;
    const u16* gB0 = B + (size_t)(n0 + r0) * K + gch * 8;
    const u16* gB1 = B + (size_t)(n0 + r1) * K + gch * 8;

#define STG_A(bf_, kt_) do {                                                  \
        ASYNC_LD16(gA0 + (kt_) * 32, lds + (bf_) * 16384 + wave * 512);       \
        ASYNC_LD16(gA1 + (kt_) * 32, lds + (bf_) * 16384 + 4096 + wave * 512);\
    } while (0)
#define STG_B(bf_, kt_) do {                                                  \
        ASYNC_LD16(gB0 + (kt_) * 32, lds + (bf_) * 16384 + 8192 + wave * 512);\
        ASYNC_LD16(gB1 + (kt_) * 32, lds + (bf_) * 16384 + 12288 + wave * 512);\
    } while (0)

    // ---- fragment read offsets (u16 units), swizzled chunk:
    // want global chunk lq of row -> read LDS chunk lq ^ ((row>>1)&3);
    // row = 16*m + fr  =>  (row>>1)&3 == (fr>>1)&3  (constant per lane).
    const int rch = lq ^ ((fr >> 1) & 3);
    const int offA0 = (wr * 128 + fr) * 32 + rch * 8;   // + mi*512
    const int offB0 = (wc * 64 + fr) * 32 + rch * 8;    // + ni*512

    f32x4 acc[8][4] = {};
    const int NT = K >> 5;              // K-tiles of 32 (NT >= 3 here)

    // prologue: fill ring with K-tiles 0,1,2 (12 loads/thread in flight)
    STG_A(0, 0); STG_B(0, 0);
    STG_A(1, 1); STG_B(1, 1);
    STG_A(2, 2); STG_B(2, 2);
    asm volatile("s_waitcnt vmcnt(8)" ::: "memory");   // K-tile 0 landed
    __builtin_amdgcn_s_barrier();

    for (int c = 0; c < NT; ++c) {
        const u16* sA = lds + (c & 3) * 16384;
        const u16* sB = sA + 8192;
        s16x8 a0[4], b0[4], a1[4];
        // ---- phase 1: mi 0..3  (8 ds_read_b128 + 2 global_load_lds)
#pragma unroll
        for (int i = 0; i < 4; ++i) a0[i] = *(const s16x8*)(sA + offA0 + i * 512);
#pragma unroll
        for (int i = 0; i < 4; ++i) b0[i] = *(const s16x8*)(sB + offB0 + i * 512);
        if (c + 3 < NT) STG_A((c + 3) & 3, c + 3);
        __builtin_amdgcn_s_barrier();
        asm volatile("s_waitcnt lgkmcnt(0)" ::: "memory");
        __builtin_amdgcn_s_setprio(1);
#pragma unroll
        for (int mi = 0; mi < 4; ++mi)
#pragma unroll
            for (int ni = 0; ni < 4; ++ni)
                acc[mi][ni] = __builtin_amdgcn_mfma_f32_16x16x32_bf16(
                    a0[mi], b0[ni], acc[mi][ni], 0, 0, 0);
        __builtin_amdgcn_s_setprio(0);
        __builtin_amdgcn_s_barrier();
        // ---- phase 2: mi 4..7  (4 ds_read_b128 + 2 global_load_lds)
#pragma unroll
        for (int i = 0; i < 4; ++i) a1[i] = *(const s16x8*)(sA + offA0 + (i + 4) * 512);
        if (c + 3 < NT) STG_B((c + 3) & 3, c + 3);
        __builtin_amdgcn_s_barrier();
        asm volatile("s_waitcnt lgkmcnt(0)" ::: "memory");
        __builtin_amdgcn_s_setprio(1);
#pragma unroll
        for (int mi = 0; mi < 4; ++mi)
#pragma unroll
            for (int ni = 0; ni < 4; ++ni)
                acc[mi + 4][ni] = __builtin_amdgcn_mfma_f32_16x16x32_bf16(
                    a1[mi], b0[ni], acc[mi + 4][ni], 0, 0, 0);
        __builtin_amdgcn_s_setprio(0);
        asm volatile("s_waitcnt vmcnt(8)" ::: "memory");   // K-tile c+1 landed
        __builtin_amdgcn_s_barrier();
    }

    // ---- epilogue. C/D layout: row = lq*4 + reg (+16*mi), col = fr (+16*ni)
    const int rowB = m0 + wr * 128 + lq * 4;
    const int colB = n0 + wc * 64 + fr;

    if constexpr (MODE == 2) {
        float inv[4];
#pragma unroll
        for (int ni = 0; ni < 4; ++ni) inv[ni] = 1.0f / sv[colB + ni * 16];
#pragma unroll
        for (int mi = 0; mi < 8; ++mi)
#pragma unroll
            for (int r = 0; r < 4; ++r) {
                const int gm = rowB + mi * 16 + r;
                float s = 0.f;
#pragma unroll
                for (int ni = 0; ni < 4; ++ni) {
                    float e = __expf(acc[mi][ni][r] * inv[ni]);
                    C[(size_t)gm * N + (colB + ni * 16)] = f2bf(e);
                    s += e;
                }
                s += __shfl_xor(s, 1);
                s += __shfl_xor(s, 2);
                s += __shfl_xor(s, 4);
                s += __shfl_xor(s, 8);
                if (fr == 0) atomicAdd(&sum_out[gm], s);
            }
    } else {  // MODE 3: fp32 out, divide by row sum
#pragma unroll
        for (int mi = 0; mi < 8; ++mi)
#pragma unroll
            for (int r = 0; r < 4; ++r) {
                const int gm = rowB + mi * 16 + r;
                const float invr = 1.0f / sv[gm];
#pragma unroll
                for (int ni = 0; ni < 4; ++ni)
                    Cf[(size_t)gm * N + (colB + ni * 16)] = acc[mi][ni][r] * invr;
            }
    }
#undef STG_A
#undef STG_B
}

extern "C" void kernel_launch(void* const* d_in, const int* in_sizes, int n_in,
                              void* d_out, int out_size, void* d_ws, size_t ws_size,
                              hipStream_t stream)
{
    (void)in_sizes; (void)n_in; (void)out_size;
    const float* kin = (const float*)d_in[0];   // 32768 x 1024 fp32
    const float* mem = (const float*)d_in[1];   // 4096 x 512
    const float* fkw = (const float*)d_in[2];   // 1024 x 512
    const float* fkb = (const float*)d_in[3];   // 1024
    const float* fvw = (const float*)d_in[4];   // 1024 x 512
    const float* fvb = (const float*)d_in[5];   // 1024
    float* out = (float*)d_out;                 // 32768 x 1024 fp32

    const int NM = 4096, MD = 512, ID = 1024, NQ = 32768;

    u16* kbf   = (u16*)d_ws;                          // NQ x ID   (64 MB)
    u16* membf = kbf   + (size_t)NQ * ID;             // NM x MD   (4 MB)
    u16* fkwbf = membf + (size_t)NM * MD;             // ID x MD   (1 MB)
    u16* fvwbf = fkwbf + (size_t)ID * MD;             // ID x MD   (1 MB)
    u16* expK  = fvwbf + (size_t)ID * MD;             // NM x ID   (8 MB)
    u16* valT  = expK  + (size_t)NM * ID;             // ID x NM   (8 MB)
    u16* P     = valT  + (size_t)ID * NM;             // NQ x NM   (256 MB)
    float* rsK = (float*)(P + (size_t)NQ * NM);       // NM
    float* rs2 = rsK + NM;                            // NQ
    const size_t needed = (size_t)((char*)(rs2 + NQ) - (char*)d_ws);
    if (ws_size < needed) return;  // diagnostic: absmax == 0.2676 exactly

    hipMemsetAsync(rsK, 0, (size_t)(NM + NQ) * sizeof(float), stream);

    // fp32 -> bf16 converts
    cvt_f32_bf16<<<(NQ * ID / 4 + 255) / 256, 256, 0, stream>>>(kin, kbf, NQ * ID / 4);
    cvt_f32_bf16<<<(NM * MD / 4 + 255) / 256, 256, 0, stream>>>(mem, membf, NM * MD / 4);
    cvt_f32_bf16<<<(ID * MD / 4 + 255) / 256, 256, 0, stream>>>(fkw, fkwbf, ID * MD / 4);
    cvt_f32_bf16<<<(ID * MD / 4 + 255) / 256, 256, 0, stream>>>(fvw, fvwbf, ID * MD / 4);

    // K1a: expK[m,i] = exp(mem @ fk_w^T + fk_b[i]); rsK[m] = row sums
    gemm_bt<0><<<dim3(ID / 128, NM / 128), 256, 0, stream>>>(
        membf, fkwbf, MD, ID, expK, nullptr, fkb, nullptr, rsK);
    // K1b: valT[i,m] = relu(fv_w @ mem^T + fv_b[i])
    gemm_bt<1><<<dim3(NM / 128, ID / 128), 256, 0, stream>>>(
        fvwbf, membf, MD, NM, valT, nullptr, fvb, nullptr, nullptr);
    // K2: P[q,m] = exp((k @ expK^T)[q,m] / rsK[m]); rs2[q] = row sums
    gemm256_bt<2><<<(NQ / 256) * (NM / 256), 512, 0, stream>>>(
        kbf, expK, ID, NM, P, nullptr, rsK, rs2, NM / 256);
    // K3: out[q,i] = (P @ valT^T)[q,i] / rs2[q]
    gemm256_bt<3><<<(NQ / 256) * (ID / 256), 512, 0, stream>>>(
        P, valT, NM, ID, nullptr, out, rs2, nullptr, ID / 256);
}

// Round 2
// 920.264 us; speedup vs baseline: 1.2263x; 1.0015x over previous
//
#include <hip/hip_runtime.h>
#include <stdint.h>

typedef unsigned short u16;
typedef short s16x8 __attribute__((ext_vector_type(8)));
typedef float f32x4 __attribute__((ext_vector_type(4)));

__device__ __forceinline__ u16 f2bf(float f) {
    union { float f; uint32_t i; } v; v.f = f;
    return (u16)((v.i + 0x7FFFu + ((v.i >> 16) & 1u)) >> 16);
}

__global__ void __launch_bounds__(256) cvt_f32_bf16(
    const float* __restrict__ src, u16* __restrict__ dst, int n4)
{
    int i = blockIdx.x * 256 + threadIdx.x;
    if (i >= n4) return;
    float4 f = ((const float4*)src)[i];
    ushort4 o;
    o.x = f2bf(f.x); o.y = f2bf(f.y); o.z = f2bf(f.z); o.w = f2bf(f.w);
    ((ushort4*)dst)[i] = o;
}

#define ASYNC_LD16(gp, lp)                                                       \
    __builtin_amdgcn_global_load_lds(                                            \
        (const __attribute__((address_space(1))) uint32_t*)(gp),                 \
        (__attribute__((address_space(3))) uint32_t*)(lp), 16, 0, 0)

// ---------------------------------------------------------------------------
// Small-GEMM kernel (verified): 128x128 tile.
// MODE 0: c += bias[col]; e=exp(c); store bf16; atomicAdd row-sums of e.
// MODE 1: c += bias[row]; store bf16 relu(c).
template <int MODE>
__global__ void __launch_bounds__(256) gemm_bt(
    const u16* __restrict__ A, const u16* __restrict__ B, int K, int N,
    u16* __restrict__ C, float* __restrict__ Cf,
    const float* __restrict__ bias,
    const float* __restrict__ sv, float* __restrict__ sum_out)
{
    __shared__ __align__(16) u16 As[128 * 32];
    __shared__ __align__(16) u16 Bs[128 * 32];

    const int tid  = threadIdx.x;
    const int lane = tid & 63;
    const int wave = tid >> 6;
    const int wx = wave & 1, wy = wave >> 1;
    const int lr = lane & 15, lq = lane >> 4;
    const int m0 = blockIdx.y * 128, n0 = blockIdx.x * 128;

    f32x4 acc[4][4] = {};

    const int srow = tid >> 2;
    const int scol = (tid & 3) * 8;
    const u16* gA = A + (size_t)(m0 + srow) * K + scol;
    const u16* gB = B + (size_t)(n0 + srow) * K + scol;
    const size_t rstep = (size_t)64 * K;
    u16* lA0 = &As[wave * 512];
    u16* lA1 = &As[2048 + wave * 512];
    u16* lB0 = &Bs[wave * 512];
    u16* lB1 = &Bs[2048 + wave * 512];

    const u16* pa = &As[(wy * 64 + lr) * 32 + lq * 8];
    const u16* pb = &Bs[(wx * 64 + lr) * 32 + lq * 8];

    for (int k0 = 0; k0 < K; k0 += 32) {
        ASYNC_LD16(gA + k0, lA0);
        ASYNC_LD16(gA + k0 + rstep, lA1);
        ASYNC_LD16(gB + k0, lB0);
        ASYNC_LD16(gB + k0 + rstep, lB1);
        __syncthreads();
        s16x8 af[4], bfr[4];
#pragma unroll
        for (int i = 0; i < 4; ++i) {
            af[i]  = *(const s16x8*)(pa + i * 512);
            bfr[i] = *(const s16x8*)(pb + i * 512);
        }
#pragma unroll
        for (int mi = 0; mi < 4; ++mi)
#pragma unroll
            for (int ni = 0; ni < 4; ++ni)
                acc[mi][ni] = __builtin_amdgcn_mfma_f32_16x16x32_bf16(
                    af[mi], bfr[ni], acc[mi][ni], 0, 0, 0);
        __syncthreads();
    }

    const int rowB = m0 + wy * 64 + lq * 4;
    const int colB = n0 + wx * 64 + lr;

    if constexpr (MODE == 0) {
        float bcol[4];
#pragma unroll
        for (int ni = 0; ni < 4; ++ni) bcol[ni] = bias[colB + ni * 16];
#pragma unroll
        for (int mi = 0; mi < 4; ++mi)
#pragma unroll
            for (int r = 0; r < 4; ++r) {
                const int gm = rowB + mi * 16 + r;
                float s = 0.f;
#pragma unroll
                for (int ni = 0; ni < 4; ++ni) {
                    float e = __expf(acc[mi][ni][r] + bcol[ni]);
                    C[(size_t)gm * N + (colB + ni * 16)] = f2bf(e);
                    s += e;
                }
                s += __shfl_xor(s, 1);
                s += __shfl_xor(s, 2);
                s += __shfl_xor(s, 4);
                s += __shfl_xor(s, 8);
                if (lr == 0) atomicAdd(&sum_out[gm], s);
            }
    } else {
#pragma unroll
        for (int mi = 0; mi < 4; ++mi)
#pragma unroll
            for (int r = 0; r < 4; ++r) {
                const int gm = rowB + mi * 16 + r;
                const float b = bias[gm];
#pragma unroll
                for (int ni = 0; ni < 4; ++ni) {
                    float c = acc[mi][ni][r] + b;
                    C[(size_t)gm * N + (colB + ni * 16)] = f2bf(c > 0.f ? c : 0.f);
                }
            }
    }
}

// ---------------------------------------------------------------------------
// Big-GEMM kernel v2: 256x256 tile, 8 waves, BK=32, 4-deep LDS ring (128 KiB).
// ONE barrier + ONE counted vmcnt(8) per K-tile; NO explicit lgkmcnt drains —
// the compiler emits minimal counted lgkm waits between ds_read and MFMA,
// and waves are free to skew so one wave's ds_reads overlap another's MFMAs.
//
// Race-freedom (single-barrier version):
//   RAW: each wave's vmcnt(8) before barrier B_c => its own tile-(c+1) loads
//        landed; all waves passing B_c => all of tile c+1 is in LDS before
//        any wave reads buf (c+1)&3 in iteration c+1.
//   WAR: staging for tile c+3 (buf (c-1)&3) is issued after B_{c-1}; every
//        wave consumed all its reads of buf (c-1)&3 (counted lgkm waits
//        before each MFMA use) before reaching B_{c-1}.
// MODE 2: e = exp(c / sv[col]); store bf16; atomicAdd row-sums of e.
// MODE 3: store fp32 (c / sv[row]) to Cf.
template <int MODE>
__global__ void __launch_bounds__(512, 2) gemm256_bt(
    const u16* __restrict__ A, const u16* __restrict__ B, int K, int N,
    u16* __restrict__ C, float* __restrict__ Cf,
    const float* __restrict__ sv, float* __restrict__ sum_out, int nbx)
{
    __shared__ __align__(16) u16 lds[4 * 16384];   // 4 bufs x (A 16K + B 16K) B

    const int tid  = threadIdx.x;
    const int lane = tid & 63;
    const int wave = tid >> 6;          // 0..7
    const int wr = wave >> 2;           // 0..1 : 128-row half
    const int wc = wave & 3;            // 0..3 : 64-col quarter
    const int fr = lane & 15;
    const int lq = lane >> 4;

    // XCD-aware bijective swizzle (gridDim.x % 8 == 0 for both uses)
    const int nwg = gridDim.x;
    const int swz = ((int)blockIdx.x & 7) * (nwg >> 3) + ((int)blockIdx.x >> 3);
    const int bx = swz % nbx, by = swz / nbx;
    const int m0 = by * 256, n0 = bx * 256;

    // staging: linear LDS dest, pre-swizzled global source.
    // LDS chunk l (16B units) = round*512 + tid; row = l>>2, c2 = l&3.
    // LDS (row,c2) holds global chunk  c2 ^ ((row>>1)&3).
    const int r0 = tid >> 2;            // rows 0..127 (round 0)
    const int r1 = r0 + 128;            // rows 128..255 (round 1), same xor
    const int gch = (tid & 3) ^ ((r0 >> 1) & 3);
    const u16* gA0 = A + (size_t)(m0 + r0) * K + gch * 8;
    const u16* gA1 = A + (size_t)(m0 + r1) * K + gch * 8;
    const u16* gB0 = B + (size_t)(n0 + r0) * K + gch * 8;
    const u16* gB1 = B + (size_t)(n0 + r1) * K + gch * 8;

#define STG_A(bf_, kt_) do {                                                  \
        ASYNC_LD16(gA0 + (kt_) * 32, lds + (bf_) * 16384 + wave * 512);       \
        ASYNC_LD16(gA1 + (kt_) * 32, lds + (bf_) * 16384 + 4096 + wave * 512);\
    } while (0)
#define STG_B(bf_, kt_) do {                                                  \
        ASYNC_LD16(gB0 + (kt_) * 32, lds + (bf_) * 16384 + 8192 + wave * 512);\
        ASYNC_LD16(gB1 + (kt_) * 32, lds + (bf_) * 16384 + 12288 + wave * 512);\
    } while (0)

    // fragment read offsets (u16 units), swizzled chunk:
    // global chunk lq of row -> LDS chunk lq ^ ((row>>1)&3);
    // row = 16*m + fr  =>  (row>>1)&3 == (fr>>1)&3 (constant per lane).
    const int rch = lq ^ ((fr >> 1) & 3);
    const int offA0 = (wr * 128 + fr) * 32 + rch * 8;   // + mi*512
    const int offB0 = (wc * 64 + fr) * 32 + rch * 8;    // + ni*512

    f32x4 acc[8][4] = {};
    const int NT = K >> 5;              // K-tiles of 32 (NT >= 4 here)

    // prologue: fill ring with K-tiles 0,1,2 (12 loads/thread in flight)
    STG_A(0, 0); STG_B(0, 0);
    STG_A(1, 1); STG_B(1, 1);
    STG_A(2, 2); STG_B(2, 2);
    asm volatile("s_waitcnt vmcnt(8)" ::: "memory");   // K-tile 0 landed
    __builtin_amdgcn_s_barrier();

    for (int c = 0; c < NT; ++c) {
        const u16* sA = lds + (c & 3) * 16384;
        const u16* sB = sA + 8192;
        // issue next-tile staging first (deepest in-flight position)
        if (c + 3 < NT) { STG_A((c + 3) & 3, c + 3); STG_B((c + 3) & 3, c + 3); }
        // fragment loads: compiler inserts minimal counted lgkm waits
        s16x8 a[8], b[4];
#pragma unroll
        for (int i = 0; i < 8; ++i) a[i] = *(const s16x8*)(sA + offA0 + i * 512);
#pragma unroll
        for (int i = 0; i < 4; ++i) b[i] = *(const s16x8*)(sB + offB0 + i * 512);
        __builtin_amdgcn_s_setprio(1);
#pragma unroll
        for (int mi = 0; mi < 8; ++mi)
#pragma unroll
            for (int ni = 0; ni < 4; ++ni)
                acc[mi][ni] = __builtin_amdgcn_mfma_f32_16x16x32_bf16(
                    a[mi], b[ni], acc[mi][ni], 0, 0, 0);
        __builtin_amdgcn_s_setprio(0);
        asm volatile("s_waitcnt vmcnt(8)" ::: "memory");   // K-tile c+1 landed
        __builtin_amdgcn_s_barrier();
    }

    // epilogue. C/D layout: row = lq*4 + reg (+16*mi), col = fr (+16*ni)
    const int rowB = m0 + wr * 128 + lq * 4;
    const int colB = n0 + wc * 64 + fr;

    if constexpr (MODE == 2) {
        float inv[4];
#pragma unroll
        for (int ni = 0; ni < 4; ++ni) inv[ni] = 1.0f / sv[colB + ni * 16];
#pragma unroll
        for (int mi = 0; mi < 8; ++mi)
#pragma unroll
            for (int r = 0; r < 4; ++r) {
                const int gm = rowB + mi * 16 + r;
                float s = 0.f;
#pragma unroll
                for (int ni = 0; ni < 4; ++ni) {
                    float e = __expf(acc[mi][ni][r] * inv[ni]);
                    C[(size_t)gm * N + (colB + ni * 16)] = f2bf(e);
                    s += e;
                }
                s += __shfl_xor(s, 1);
                s += __shfl_xor(s, 2);
                s += __shfl_xor(s, 4);
                s += __shfl_xor(s, 8);
                if (fr == 0) atomicAdd(&sum_out[gm], s);
            }
    } else {  // MODE 3: fp32 out, divide by row sum
#pragma unroll
        for (int mi = 0; mi < 8; ++mi)
#pragma unroll
            for (int r = 0; r < 4; ++r) {
                const int gm = rowB + mi * 16 + r;
                const float invr = 1.0f / sv[gm];
#pragma unroll
                for (int ni = 0; ni < 4; ++ni)
                    Cf[(size_t)gm * N + (colB + ni * 16)] = acc[mi][ni][r] * invr;
            }
    }
#undef STG_A
#undef STG_B
}

extern "C" void kernel_launch(void* const* d_in, const int* in_sizes, int n_in,
                              void* d_out, int out_size, void* d_ws, size_t ws_size,
                              hipStream_t stream)
{
    (void)in_sizes; (void)n_in; (void)out_size;
    const float* kin = (const float*)d_in[0];   // 32768 x 1024 fp32
    const float* mem = (const float*)d_in[1];   // 4096 x 512
    const float* fkw = (const float*)d_in[2];   // 1024 x 512
    const float* fkb = (const float*)d_in[3];   // 1024
    const float* fvw = (const float*)d_in[4];   // 1024 x 512
    const float* fvb = (const float*)d_in[5];   // 1024
    float* out = (float*)d_out;                 // 32768 x 1024 fp32

    const int NM = 4096, MD = 512, ID = 1024, NQ = 32768;

    u16* kbf   = (u16*)d_ws;                          // NQ x ID   (64 MB)
    u16* membf = kbf   + (size_t)NQ * ID;             // NM x MD   (4 MB)
    u16* fkwbf = membf + (size_t)NM * MD;             // ID x MD   (1 MB)
    u16* fvwbf = fkwbf + (size_t)ID * MD;             // ID x MD   (1 MB)
    u16* expK  = fvwbf + (size_t)ID * MD;             // NM x ID   (8 MB)
    u16* valT  = expK  + (size_t)NM * ID;             // ID x NM   (8 MB)
    u16* P     = valT  + (size_t)ID * NM;             // NQ x NM   (256 MB)
    float* rsK = (float*)(P + (size_t)NQ * NM);       // NM
    float* rs2 = rsK + NM;                            // NQ
    const size_t needed = (size_t)((char*)(rs2 + NQ) - (char*)d_ws);
    if (ws_size < needed) return;  // diagnostic: absmax == 0.2676 exactly

    hipMemsetAsync(rsK, 0, (size_t)(NM + NQ) * sizeof(float), stream);

    // fp32 -> bf16 converts
    cvt_f32_bf16<<<(NQ * ID / 4 + 255) / 256, 256, 0, stream>>>(kin, kbf, NQ * ID / 4);
    cvt_f32_bf16<<<(NM * MD / 4 + 255) / 256, 256, 0, stream>>>(mem, membf, NM * MD / 4);
    cvt_f32_bf16<<<(ID * MD / 4 + 255) / 256, 256, 0, stream>>>(fkw, fkwbf, ID * MD / 4);
    cvt_f32_bf16<<<(ID * MD / 4 + 255) / 256, 256, 0, stream>>>(fvw, fvwbf, ID * MD / 4);

    // K1a: expK[m,i] = exp(mem @ fk_w^T + fk_b[i]); rsK[m] = row sums
    gemm_bt<0><<<dim3(ID / 128, NM / 128), 256, 0, stream>>>(
        membf, fkwbf, MD, ID, expK, nullptr, fkb, nullptr, rsK);
    // K1b: valT[i,m] = relu(fv_w @ mem^T + fv_b[i])
    gemm_bt<1><<<dim3(NM / 128, ID / 128), 256, 0, stream>>>(
        fvwbf, membf, MD, NM, valT, nullptr, fvb, nullptr, nullptr);
    // K2: P[q,m] = exp((k @ expK^T)[q,m] / rsK[m]); rs2[q] = row sums
    gemm256_bt<2><<<(NQ / 256) * (NM / 256), 512, 0, stream>>>(
        kbf, expK, ID, NM, P, nullptr, rsK, rs2, NM / 256);
    // K3: out[q,i] = (P @ valT^T)[q,i] / rs2[q]
    gemm256_bt<3><<<(NQ / 256) * (ID / 256), 512, 0, stream>>>(
        P, valT, NM, ID, nullptr, out, rs2, nullptr, ID / 256);
}

// Round 3
// 902.851 us; speedup vs baseline: 1.2499x; 1.0193x over previous
//
#include <hip/hip_runtime.h>
#include <stdint.h>

typedef unsigned short u16;
typedef short s16x8 __attribute__((ext_vector_type(8)));
typedef float f32x4 __attribute__((ext_vector_type(4)));

__device__ __forceinline__ u16 f2bf(float f) {
    union { float f; uint32_t i; } v; v.f = f;
    return (u16)((v.i + 0x7FFFu + ((v.i >> 16) & 1u)) >> 16);
}

__global__ void __launch_bounds__(256) cvt_f32_bf16(
    const float* __restrict__ src, u16* __restrict__ dst, int n4)
{
    int i = blockIdx.x * 256 + threadIdx.x;
    if (i >= n4) return;
    float4 f = ((const float4*)src)[i];
    ushort4 o;
    o.x = f2bf(f.x); o.y = f2bf(f.y); o.z = f2bf(f.z); o.w = f2bf(f.w);
    ((ushort4*)dst)[i] = o;
}

#define ASYNC_LD16(gp, lp)                                                       \
    __builtin_amdgcn_global_load_lds(                                            \
        (const __attribute__((address_space(1))) uint32_t*)(gp),                 \
        (__attribute__((address_space(3))) uint32_t*)(lp), 16, 0, 0)

// ---------------------------------------------------------------------------
// Small-GEMM kernel (verified): 128x128 tile.
// MODE 0: c += bias[col]; e=exp(c); store bf16; atomicAdd row-sums of e.
// MODE 1: c += bias[row]; store bf16 relu(c).
template <int MODE>
__global__ void __launch_bounds__(256) gemm_bt(
    const u16* __restrict__ A, const u16* __restrict__ B, int K, int N,
    u16* __restrict__ C, float* __restrict__ Cf,
    const float* __restrict__ bias,
    const float* __restrict__ sv, float* __restrict__ sum_out)
{
    __shared__ __align__(16) u16 As[128 * 32];
    __shared__ __align__(16) u16 Bs[128 * 32];

    const int tid  = threadIdx.x;
    const int lane = tid & 63;
    const int wave = tid >> 6;
    const int wx = wave & 1, wy = wave >> 1;
    const int lr = lane & 15, lq = lane >> 4;
    const int m0 = blockIdx.y * 128, n0 = blockIdx.x * 128;

    f32x4 acc[4][4] = {};

    const int srow = tid >> 2;
    const int scol = (tid & 3) * 8;
    const u16* gA = A + (size_t)(m0 + srow) * K + scol;
    const u16* gB = B + (size_t)(n0 + srow) * K + scol;
    const size_t rstep = (size_t)64 * K;
    u16* lA0 = &As[wave * 512];
    u16* lA1 = &As[2048 + wave * 512];
    u16* lB0 = &Bs[wave * 512];
    u16* lB1 = &Bs[2048 + wave * 512];

    const u16* pa = &As[(wy * 64 + lr) * 32 + lq * 8];
    const u16* pb = &Bs[(wx * 64 + lr) * 32 + lq * 8];

    for (int k0 = 0; k0 < K; k0 += 32) {
        ASYNC_LD16(gA + k0, lA0);
        ASYNC_LD16(gA + k0 + rstep, lA1);
        ASYNC_LD16(gB + k0, lB0);
        ASYNC_LD16(gB + k0 + rstep, lB1);
        __syncthreads();
        s16x8 af[4], bfr[4];
#pragma unroll
        for (int i = 0; i < 4; ++i) {
            af[i]  = *(const s16x8*)(pa + i * 512);
            bfr[i] = *(const s16x8*)(pb + i * 512);
        }
#pragma unroll
        for (int mi = 0; mi < 4; ++mi)
#pragma unroll
            for (int ni = 0; ni < 4; ++ni)
                acc[mi][ni] = __builtin_amdgcn_mfma_f32_16x16x32_bf16(
                    af[mi], bfr[ni], acc[mi][ni], 0, 0, 0);
        __syncthreads();
    }

    const int rowB = m0 + wy * 64 + lq * 4;
    const int colB = n0 + wx * 64 + lr;

    if constexpr (MODE == 0) {
        float bcol[4];
#pragma unroll
        for (int ni = 0; ni < 4; ++ni) bcol[ni] = bias[colB + ni * 16];
#pragma unroll
        for (int mi = 0; mi < 4; ++mi)
#pragma unroll
            for (int r = 0; r < 4; ++r) {
                const int gm = rowB + mi * 16 + r;
                float s = 0.f;
#pragma unroll
                for (int ni = 0; ni < 4; ++ni) {
                    float e = __expf(acc[mi][ni][r] + bcol[ni]);
                    C[(size_t)gm * N + (colB + ni * 16)] = f2bf(e);
                    s += e;
                }
                s += __shfl_xor(s, 1);
                s += __shfl_xor(s, 2);
                s += __shfl_xor(s, 4);
                s += __shfl_xor(s, 8);
                if (lr == 0) atomicAdd(&sum_out[gm], s);
            }
    } else {
#pragma unroll
        for (int mi = 0; mi < 4; ++mi)
#pragma unroll
            for (int r = 0; r < 4; ++r) {
                const int gm = rowB + mi * 16 + r;
                const float b = bias[gm];
#pragma unroll
                for (int ni = 0; ni < 4; ++ni) {
                    float c = acc[mi][ni][r] + b;
                    C[(size_t)gm * N + (colB + ni * 16)] = f2bf(c > 0.f ? c : 0.f);
                }
            }
    }
}

// ---------------------------------------------------------------------------
// Big-GEMM kernel v3: 256x256 tile, 8 waves, BK=32, 4-deep LDS ring (128 KiB),
// CROSS-ITERATION ds_read software pipeline:
//   - aLo fragments of tile c+1 are read DURING iteration c (buffer (c+1)&3
//     is already valid then), ping-ponged between two register sets.
//   - b / aHi fragments are read at the top of their own phase (single-buffered
//     to stay under the 256-reg occupancy cliff).
//   => each MFMA cluster starts on registers that are already resident or on
//      reads issued a phase earlier (cheap counted lgkm waits), and next-tile
//      reads flow under the current MFMA cluster on the same wave.
// ONE barrier + ONE counted vmcnt(4) per K-tile.
//
// Race-freedom:
//   RAW: vmcnt(4) at end of iter c leaves only tile (c+3)'s 4 loads
//        outstanding => tiles <= c+2 landed; barrier publishes to all waves.
//        Reads of tile c+1 during iter c need tiles <= c+1 landed by the end
//        of iter c-1: vmcnt(4) there leaves only tile (c+2)'s loads. OK.
//        Prologue: 12 loads, vmcnt(4) => tiles 0,1 landed before iter 0.
//   WAR: STG(c+3) targets buf (c-1)&3, issued after barrier B_{c-1}; every
//        wave's reads of buf (c-1)&3 were lgkm-waited before its MFMA uses,
//        which precede B_{c-1}.
// MODE 2: e = exp(c / sv[col]); store bf16; atomicAdd row-sums of e.
// MODE 3: store fp32 (c / sv[row]) to Cf.
template <int MODE>
__global__ void __launch_bounds__(512, 2) gemm256_bt(
    const u16* __restrict__ A, const u16* __restrict__ B, int K, int N,
    u16* __restrict__ C, float* __restrict__ Cf,
    const float* __restrict__ sv, float* __restrict__ sum_out, int nbx)
{
    __shared__ __align__(16) u16 lds[4 * 16384];   // 4 bufs x (A 16K + B 16K) B

    const int tid  = threadIdx.x;
    const int lane = tid & 63;
    const int wave = tid >> 6;          // 0..7
    const int wr = wave >> 2;           // 0..1 : 128-row half
    const int wc = wave & 3;            // 0..3 : 64-col quarter
    const int fr = lane & 15;
    const int lq = lane >> 4;

    // XCD-aware bijective swizzle (gridDim.x % 8 == 0 for both uses)
    const int nwg = gridDim.x;
    const int swz = ((int)blockIdx.x & 7) * (nwg >> 3) + ((int)blockIdx.x >> 3);
    const int bx = swz % nbx, by = swz / nbx;
    const int m0 = by * 256, n0 = bx * 256;

    // staging: linear LDS dest, pre-swizzled global source.
    // LDS chunk l (16B units) = round*512 + tid; row = l>>2, c2 = l&3.
    // LDS (row,c2) holds global chunk  c2 ^ ((row>>1)&3).
    const int r0 = tid >> 2;            // rows 0..127 (round 0)
    const int r1 = r0 + 128;            // rows 128..255 (round 1), same xor
    const int gch = (tid & 3) ^ ((r0 >> 1) & 3);
    const u16* gA0 = A + (size_t)(m0 + r0) * K + gch * 8;
    const u16* gA1 = A + (size_t)(m0 + r1) * K + gch * 8;
    const u16* gB0 = B + (size_t)(n0 + r0) * K + gch * 8;
    const u16* gB1 = B + (size_t)(n0 + r1) * K + gch * 8;

#define STG_A(bf_, kt_) do {                                                  \
        ASYNC_LD16(gA0 + (kt_) * 32, lds + (bf_) * 16384 + wave * 512);       \
        ASYNC_LD16(gA1 + (kt_) * 32, lds + (bf_) * 16384 + 4096 + wave * 512);\
    } while (0)
#define STG_B(bf_, kt_) do {                                                  \
        ASYNC_LD16(gB0 + (kt_) * 32, lds + (bf_) * 16384 + 8192 + wave * 512);\
        ASYNC_LD16(gB1 + (kt_) * 32, lds + (bf_) * 16384 + 12288 + wave * 512);\
    } while (0)

    // fragment read offsets (u16 units), swizzled chunk:
    // global chunk lq of row -> LDS chunk lq ^ ((row>>1)&3);
    // row = 16*m + fr  =>  (row>>1)&3 == (fr>>1)&3 (constant per lane).
    const int rch = lq ^ ((fr >> 1) & 3);
    const int offA = (wr * 128 + fr) * 32 + rch * 8;          // + mi*512
    const int offB = (wc * 64 + fr) * 32 + rch * 8 + 8192;    // + ni*512

    f32x4 acc[8][4] = {};
    const int NT = K >> 5;              // K-tiles of 32 (even, >= 4 here)

    // prologue: fill ring with K-tiles 0,1,2
    STG_A(0, 0); STG_B(0, 0);
    STG_A(1, 1); STG_B(1, 1);
    STG_A(2, 2); STG_B(2, 2);
    asm volatile("s_waitcnt vmcnt(4)" ::: "memory");   // K-tiles 0,1 landed
    __builtin_amdgcn_s_barrier();
    __builtin_amdgcn_sched_barrier(0);

    s16x8 aLo0[4], aLo1[4], aHi[4], bv[4];
#pragma unroll
    for (int i = 0; i < 4; ++i)
        aLo0[i] = *(const s16x8*)(lds + offA + i * 512);   // tile 0, buf 0

    // One iteration: PhA {read bv+aHi of tile c, stage A of c+3,
    //                     MFMA aLo x bv (mi 0-3)},
    //                PhB {read next tile's aLo (buf c+1), stage B of c+3,
    //                     MFMA aHi x bv (mi 4-7)}, vmcnt(4), barrier.
#define ITER(c_, AL, ALN)                                                     \
    {                                                                         \
        const u16* sCur = lds + ((c_) & 3) * 16384;                           \
        const u16* sNxt = lds + (((c_) + 1) & 3) * 16384;                     \
        _Pragma("unroll") for (int i = 0; i < 4; ++i)                         \
            bv[i] = *(const s16x8*)(sCur + offB + i * 512);                   \
        _Pragma("unroll") for (int i = 0; i < 4; ++i)                         \
            aHi[i] = *(const s16x8*)(sCur + offA + (i + 4) * 512);            \
        if ((c_) + 3 < NT) STG_A(((c_) + 3) & 3, (c_) + 3);                   \
        __builtin_amdgcn_s_setprio(1);                                        \
        _Pragma("unroll") for (int mi = 0; mi < 4; ++mi)                      \
            _Pragma("unroll") for (int ni = 0; ni < 4; ++ni)                  \
                acc[mi][ni] = __builtin_amdgcn_mfma_f32_16x16x32_bf16(        \
                    AL[mi], bv[ni], acc[mi][ni], 0, 0, 0);                    \
        __builtin_amdgcn_s_setprio(0);                                        \
        _Pragma("unroll") for (int i = 0; i < 4; ++i)                         \
            ALN[i] = *(const s16x8*)(sNxt + offA + i * 512);                  \
        if ((c_) + 3 < NT) STG_B(((c_) + 3) & 3, (c_) + 3);                   \
        __builtin_amdgcn_s_setprio(1);                                        \
        _Pragma("unroll") for (int mi = 0; mi < 4; ++mi)                      \
            _Pragma("unroll") for (int ni = 0; ni < 4; ++ni)                  \
                acc[mi + 4][ni] = __builtin_amdgcn_mfma_f32_16x16x32_bf16(    \
                    aHi[mi], bv[ni], acc[mi + 4][ni], 0, 0, 0);               \
        __builtin_amdgcn_s_setprio(0);                                        \
        asm volatile("s_waitcnt vmcnt(4)" ::: "memory");                      \
        __builtin_amdgcn_s_barrier();                                         \
        __builtin_amdgcn_sched_barrier(0);                                    \
    }

    for (int c = 0; c < NT; c += 2) {
        ITER(c,     aLo0, aLo1);
        ITER(c + 1, aLo1, aLo0);   // last pass reads a stale buf; values unused
    }
#undef ITER
#undef STG_A
#undef STG_B

    // epilogue. C/D layout: row = lq*4 + reg (+16*mi), col = fr (+16*ni)
    const int rowB = m0 + wr * 128 + lq * 4;
    const int colB = n0 + wc * 64 + fr;

    if constexpr (MODE == 2) {
        float inv[4];
#pragma unroll
        for (int ni = 0; ni < 4; ++ni) inv[ni] = 1.0f / sv[colB + ni * 16];
#pragma unroll
        for (int mi = 0; mi < 8; ++mi)
#pragma unroll
            for (int r = 0; r < 4; ++r) {
                const int gm = rowB + mi * 16 + r;
                float s = 0.f;
#pragma unroll
                for (int ni = 0; ni < 4; ++ni) {
                    float e = __expf(acc[mi][ni][r] * inv[ni]);
                    C[(size_t)gm * N + (colB + ni * 16)] = f2bf(e);
                    s += e;
                }
                s += __shfl_xor(s, 1);
                s += __shfl_xor(s, 2);
                s += __shfl_xor(s, 4);
                s += __shfl_xor(s, 8);
                if (fr == 0) atomicAdd(&sum_out[gm], s);
            }
    } else {  // MODE 3: fp32 out, divide by row sum
#pragma unroll
        for (int mi = 0; mi < 8; ++mi)
#pragma unroll
            for (int r = 0; r < 4; ++r) {
                const int gm = rowB + mi * 16 + r;
                const float invr = 1.0f / sv[gm];
#pragma unroll
                for (int ni = 0; ni < 4; ++ni)
                    Cf[(size_t)gm * N + (colB + ni * 16)] = acc[mi][ni][r] * invr;
            }
    }
}

extern "C" void kernel_launch(void* const* d_in, const int* in_sizes, int n_in,
                              void* d_out, int out_size, void* d_ws, size_t ws_size,
                              hipStream_t stream)
{
    (void)in_sizes; (void)n_in; (void)out_size;
    const float* kin = (const float*)d_in[0];   // 32768 x 1024 fp32
    const float* mem = (const float*)d_in[1];   // 4096 x 512
    const float* fkw = (const float*)d_in[2];   // 1024 x 512
    const float* fkb = (const float*)d_in[3];   // 1024
    const float* fvw = (const float*)d_in[4];   // 1024 x 512
    const float* fvb = (const float*)d_in[5];   // 1024
    float* out = (float*)d_out;                 // 32768 x 1024 fp32

    const int NM = 4096, MD = 512, ID = 1024, NQ = 32768;

    u16* kbf   = (u16*)d_ws;                          // NQ x ID   (64 MB)
    u16* membf = kbf   + (size_t)NQ * ID;             // NM x MD   (4 MB)
    u16* fkwbf = membf + (size_t)NM * MD;             // ID x MD   (1 MB)
    u16* fvwbf = fkwbf + (size_t)ID * MD;             // ID x MD   (1 MB)
    u16* expK  = fvwbf + (size_t)ID * MD;             // NM x ID   (8 MB)
    u16* valT  = expK  + (size_t)NM * ID;             // ID x NM   (8 MB)
    u16* P     = valT  + (size_t)ID * NM;             // NQ x NM   (256 MB)
    float* rsK = (float*)(P + (size_t)NQ * NM);       // NM
    float* rs2 = rsK + NM;                            // NQ
    const size_t needed = (size_t)((char*)(rs2 + NQ) - (char*)d_ws);
    if (ws_size < needed) return;  // diagnostic: absmax == 0.2676 exactly

    hipMemsetAsync(rsK, 0, (size_t)(NM + NQ) * sizeof(float), stream);

    // fp32 -> bf16 converts
    cvt_f32_bf16<<<(NQ * ID / 4 + 255) / 256, 256, 0, stream>>>(kin, kbf, NQ * ID / 4);
    cvt_f32_bf16<<<(NM * MD / 4 + 255) / 256, 256, 0, stream>>>(mem, membf, NM * MD / 4);
    cvt_f32_bf16<<<(ID * MD / 4 + 255) / 256, 256, 0, stream>>>(fkw, fkwbf, ID * MD / 4);
    cvt_f32_bf16<<<(ID * MD / 4 + 255) / 256, 256, 0, stream>>>(fvw, fvwbf, ID * MD / 4);

    // K1a: expK[m,i] = exp(mem @ fk_w^T + fk_b[i]); rsK[m] = row sums
    gemm_bt<0><<<dim3(ID / 128, NM / 128), 256, 0, stream>>>(
        membf, fkwbf, MD, ID, expK, nullptr, fkb, nullptr, rsK);
    // K1b: valT[i,m] = relu(fv_w @ mem^T + fv_b[i])
    gemm_bt<1><<<dim3(NM / 128, ID / 128), 256, 0, stream>>>(
        fvwbf, membf, MD, NM, valT, nullptr, fvb, nullptr, nullptr);
    // K2: P[q,m] = exp((k @ expK^T)[q,m] / rsK[m]); rs2[q] = row sums
    gemm256_bt<2><<<(NQ / 256) * (NM / 256), 512, 0, stream>>>(
        kbf, expK, ID, NM, P, nullptr, rsK, rs2, NM / 256);
    // K3: out[q,i] = (P @ valT^T)[q,i] / rs2[q]
    gemm256_bt<3><<<(NQ / 256) * (ID / 256), 512, 0, stream>>>(
        P, valT, NM, ID, nullptr, out, rs2, nullptr, ID / 256);
}